// Round 4
// baseline (889.552 us; speedup 1.0000x reference)
//
#include <hip/hip_runtime.h>

typedef unsigned short u16;
typedef unsigned int u32;
typedef __attribute__((ext_vector_type(8))) short bf16x8;
typedef __attribute__((ext_vector_type(4))) float f32x4;

__device__ __forceinline__ float bf2f(u16 h) {
  union { unsigned u; float f; } v; v.u = ((unsigned)h) << 16; return v.f;
}
__device__ __forceinline__ u16 f2bf(float f) {
  union { float f; unsigned u; } v; v.f = f;
  unsigned r = (v.u + 0x7FFFu + ((v.u >> 16) & 1u)) >> 16;
  return (u16)r;
}
__device__ __forceinline__ u32 pack2(u16 a, u16 b) { return (u32)a | ((u32)b << 16); }
__device__ __forceinline__ void gload_lds16(const void* g, void* l) {
  __builtin_amdgcn_global_load_lds((const __attribute__((address_space(1))) void*)g,
                                   (__attribute__((address_space(3))) void*)l,
                                   16, 0, 0);
}

// ---------------- prep kernels ----------------
__global__ __launch_bounds__(256) void cast_x_kernel(const float* __restrict__ X, u16* __restrict__ Xb) {
  size_t i = ((size_t)blockIdx.x * 256 + threadIdx.x) * 4;
  float4 v = *(const float4*)&X[i];
  u32 w0 = pack2(f2bf(v.x), f2bf(v.y));
  u32 w1 = pack2(f2bf(v.z), f2bf(v.w));
  *(uint2*)&Xb[i] = make_uint2(w0, w1);
}

__global__ __launch_bounds__(256) void prep_wqkv_kernel(const float* __restrict__ Wq, const float* __restrict__ Wk,
                                                        const float* __restrict__ Wv, u16* __restrict__ Wt) {
  int idx = blockIdx.x * 256 + threadIdx.x;          // over 2304*768, Wt[n][k] = W[k][n]
  if (idx >= 2304 * 768) return;
  int nn = idx / 768, k = idx - nn * 768;
  const float* src = (nn < 768) ? Wq : ((nn < 1536) ? Wk : Wv);
  int col = (nn < 768) ? nn : ((nn < 1536) ? nn - 768 : nn - 1536);
  Wt[idx] = f2bf(src[(size_t)k * 768 + col]);
}

__global__ __launch_bounds__(256) void prep_wo_kernel(const float* __restrict__ Wo, u16* __restrict__ Wt) {
  int idx = blockIdx.x * 256 + threadIdx.x;          // over 768*768
  if (idx >= 768 * 768) return;
  int nn = idx / 768, k = idx - nn * 768;
  Wt[idx] = f2bf(Wo[(size_t)k * 768 + nn]);
}

__global__ __launch_bounds__(256) void prep_bias_kernel(const float* __restrict__ bq, const float* __restrict__ bk,
                                                        const float* __restrict__ bv, float* __restrict__ bqkv) {
  int idx = blockIdx.x * 256 + threadIdx.x;
  if (idx >= 2304) return;
  bqkv[idx] = (idx < 768) ? bq[idx] : ((idx < 1536) ? bk[idx - 768] : bv[idx - 1536]);
}

// ---------------- bf16 MFMA GEMM: C[M,N] = A[M,768] @ Bt[N,768]^T ----------------
// EPI 0: C = bf16(acc + bias[col])            -> Cbf
// EPI 1: Cf = acc + bias[col] + resid[row,col] (fp32)
template <int EPI>
__global__ __launch_bounds__(256) void gemm_kernel(const u16* __restrict__ A, const u16* __restrict__ Bt,
                                                   int N, const float* __restrict__ bias,
                                                   u16* __restrict__ Cbf,
                                                   const float* __restrict__ resid, float* __restrict__ Cf) {
  __shared__ __align__(16) u16 As[128 * 64];
  __shared__ __align__(16) u16 Bs[128 * 64];
  const int tid = threadIdx.x, lane = tid & 63, wid = tid >> 6;
  const int wr = wid >> 1, wc = wid & 1;
  const int m0 = blockIdx.x * 128, n0 = blockIdx.y * 128;
  const int lrow = lane >> 3, lcol = (lane & 7) * 8;
  f32x4 acc[4][4] = {};
  for (int k0 = 0; k0 < 768; k0 += 64) {
    #pragma unroll
    for (int it = 0; it < 4; ++it) {
      int r = it * 32 + wid * 8;
      gload_lds16(A + (size_t)(m0 + r + lrow) * 768 + k0 + lcol, &As[r * 64]);
      gload_lds16(Bt + (size_t)(n0 + r + lrow) * 768 + k0 + lcol, &Bs[r * 64]);
    }
    __syncthreads();
    #pragma unroll
    for (int kk = 0; kk < 64; kk += 32) {
      bf16x8 af[4], bfm[4];
      #pragma unroll
      for (int m = 0; m < 4; ++m)
        af[m] = *(const bf16x8*)&As[(wr * 64 + m * 16 + (lane & 15)) * 64 + kk + (lane >> 4) * 8];
      #pragma unroll
      for (int n = 0; n < 4; ++n)
        bfm[n] = *(const bf16x8*)&Bs[(wc * 64 + n * 16 + (lane & 15)) * 64 + kk + (lane >> 4) * 8];
      #pragma unroll
      for (int m = 0; m < 4; ++m)
        #pragma unroll
        for (int n = 0; n < 4; ++n)
          acc[m][n] = __builtin_amdgcn_mfma_f32_16x16x32_bf16(af[m], bfm[n], acc[m][n], 0, 0, 0);
    }
    __syncthreads();
  }
  #pragma unroll
  for (int m = 0; m < 4; ++m)
    #pragma unroll
    for (int n = 0; n < 4; ++n)
      #pragma unroll
      for (int r = 0; r < 4; ++r) {
        int row = m0 + wr * 64 + m * 16 + (lane >> 4) * 4 + r;
        int col = n0 + wc * 64 + n * 16 + (lane & 15);
        float v = acc[m][n][r] + bias[col];
        size_t idx = (size_t)row * N + col;
        if (EPI == 0) Cbf[idx] = f2bf(v);
        else          Cf[idx] = v + resid[idx];
      }
}

// ---------------- per-position 12x12 head attention ----------------
// QKV bf16 [32768][2304] (q|k|v, each 12*64). Writes ctx in [B][NH][S][HD] layout (bf16),
// which IS the torch-contiguous view [B][768][4096] fed to the conv.
__global__ __launch_bounds__(128) void attn_kernel(const u16* __restrict__ QKV, u16* __restrict__ CtxT) {
  __shared__ __align__(16) u16 sm[8 * 2304];
  const int tid = threadIdx.x;
  const int p0 = blockIdx.x * 8;
  for (int idx = tid; idx < 8 * 288; idx += 128) {
    int rl = idx / 288, ch = idx - rl * 288;
    *(uint4*)&sm[rl * 2304 + ch * 8] = *(const uint4*)&QKV[(size_t)(p0 + rl) * 2304 + ch * 8];
  }
  __syncthreads();
  const int g = tid >> 4, j = tid & 15;
  if (j >= 12) return;
  const int row = p0 + g;
  const int b = row >> 12, s = row & 4095;
  const u16* q = &sm[g * 2304 + j * 64];
  const u16* kk = &sm[g * 2304 + 768];
  const u16* vv = &sm[g * 2304 + 1536];
  float qf[64];
  #pragma unroll
  for (int d = 0; d < 64; ++d) qf[d] = bf2f(q[d]);
  float sc[12];
  #pragma unroll
  for (int m = 0; m < 12; ++m) {
    float dot = 0.f;
    #pragma unroll
    for (int d = 0; d < 64; ++d) dot += qf[d] * bf2f(kk[m * 64 + d]);
    sc[m] = dot * 0.125f;
  }
  float mx = sc[0];
  #pragma unroll
  for (int m = 1; m < 12; ++m) mx = fmaxf(mx, sc[m]);
  float sum = 0.f;
  #pragma unroll
  for (int m = 0; m < 12; ++m) { sc[m] = __expf(sc[m] - mx); sum += sc[m]; }
  float inv = 1.f / sum;
  #pragma unroll
  for (int m = 0; m < 12; ++m) sc[m] *= inv;
  u16* outp = &CtxT[(((size_t)b * 12 + j) * 4096 + s) * 64];
  #pragma unroll
  for (int c = 0; c < 8; ++c) {
    float a[8] = {0, 0, 0, 0, 0, 0, 0, 0};
    #pragma unroll
    for (int m = 0; m < 12; ++m)
      #pragma unroll
      for (int e = 0; e < 8; ++e) a[e] += sc[m] * bf2f(vv[m * 64 + c * 8 + e]);
    uint4 st;
    st.x = pack2(f2bf(a[0]), f2bf(a[1]));
    st.y = pack2(f2bf(a[2]), f2bf(a[3]));
    st.z = pack2(f2bf(a[4]), f2bf(a[5]));
    st.w = pack2(f2bf(a[6]), f2bf(a[7]));
    *(uint4*)&outp[c * 8] = st;
  }
}

// ---------------- grouped conv along flat axis ----------------
// In: CtxT [B][768][4096] bf16. W fp32 [768][64][7]. Out written permuted to A2[b][s2][h2] bf16.
__global__ __launch_bounds__(256) void conv_kernel(const u16* __restrict__ CtxT, const float* __restrict__ W,
                                                   const float* __restrict__ Bc, u16* __restrict__ A2) {
  __shared__ __align__(16) u16 ins[64][72];   // 70 used (64 + 2*3 halo)
  const int blk = blockIdx.x;
  const int pt = blk & 63;                    // position block (64 positions)
  const int g = (blk >> 6) % 12;              // group
  const int b = blk / (64 * 12);              // batch
  const int tid = threadIdx.x;
  const size_t inbase = ((size_t)(b * 12 + g) * 64) * 4096;
  for (int idx = tid; idx < 64 * 70; idx += 256) {
    int i = idx / 70, cl = idx - i * 70;
    int gp = pt * 64 - 3 + cl;
    u16 v = 0;
    if (gp >= 0 && gp < 4096) v = CtxT[inbase + (size_t)i * 4096 + gp];
    ins[i][cl] = v;
  }
  __syncthreads();
  const int cl_ = tid >> 2;       // out channel within group, 0..63
  const int psub = tid & 3;       // 16-wide p slice
  const int c = g * 64 + cl_;
  const float* wrow = W + (size_t)c * 448;
  float acc[16] = {};
  for (int i = 0; i < 64; ++i) {
    float w[7];
    #pragma unroll
    for (int t = 0; t < 7; ++t) w[t] = wrow[i * 7 + t];
    union { uint4 v; u16 u[8]; } r0, r1, r2;
    r0.v = *(const uint4*)&ins[i][psub * 16];
    r1.v = *(const uint4*)&ins[i][psub * 16 + 8];
    r2.v = *(const uint4*)&ins[i][psub * 16 + 16];
    float win[24];
    #pragma unroll
    for (int t = 0; t < 8; ++t) { win[t] = bf2f(r0.u[t]); win[8 + t] = bf2f(r1.u[t]); win[16 + t] = bf2f(r2.u[t]); }
    #pragma unroll
    for (int jj = 0; jj < 16; ++jj) {
      float s_ = acc[jj];
      #pragma unroll
      for (int dk = 0; dk < 7; ++dk) s_ += win[jj + dk] * w[dk];
      acc[jj] = s_;
    }
  }
  const float bc = Bc[c];
  // (c,p) -> s2 = (c%64)*64 + p/64, h2 = (c/64)*64 + p%64  (torch contiguous-view permutation)
  int s2 = cl_ * 64 + pt;
  size_t ob = ((size_t)b * 4096 + s2) * 768 + g * 64 + psub * 16;
  u16 o[16];
  #pragma unroll
  for (int jj = 0; jj < 16; ++jj) o[jj] = f2bf(acc[jj] + bc);
  uint4 s0v, s1v;
  s0v.x = pack2(o[0], o[1]);  s0v.y = pack2(o[2], o[3]);
  s0v.z = pack2(o[4], o[5]);  s0v.w = pack2(o[6], o[7]);
  s1v.x = pack2(o[8], o[9]);  s1v.y = pack2(o[10], o[11]);
  s1v.z = pack2(o[12], o[13]); s1v.w = pack2(o[14], o[15]);
  *(uint4*)&A2[ob] = s0v;
  *(uint4*)&A2[ob + 8] = s1v;
}

// ---------------- LayerNorm -> FLOAT32 output ----------------
__global__ __launch_bounds__(256) void ln_kernel(const float* __restrict__ res, const float* __restrict__ gamma,
                                                 const float* __restrict__ beta, float* __restrict__ out) {
  const int row = blockIdx.x, tid = threadIdx.x;
  const float* x = res + (size_t)row * 768;
  float v0 = x[tid], v1 = x[tid + 256], v2 = x[tid + 512];
  float s = v0 + v1 + v2;
  float q = v0 * v0 + v1 * v1 + v2 * v2;
  #pragma unroll
  for (int off = 32; off > 0; off >>= 1) { s += __shfl_down(s, off, 64); q += __shfl_down(q, off, 64); }
  __shared__ float sh[8];
  int w = tid >> 6;
  if ((tid & 63) == 0) { sh[w] = s; sh[4 + w] = q; }
  __syncthreads();
  float S = sh[0] + sh[1] + sh[2] + sh[3];
  float Q = sh[4] + sh[5] + sh[6] + sh[7];
  float mu = S * (1.0f / 768.0f);
  float var = Q * (1.0f / 768.0f) - mu * mu;
  float inv = rsqrtf(var + 1e-12f);
  float* o = out + (size_t)row * 768;
  o[tid]       = gamma[tid] * (v0 - mu) * inv + beta[tid];
  o[tid + 256] = gamma[tid + 256] * (v1 - mu) * inv + beta[tid + 256];
  o[tid + 512] = gamma[tid + 512] * (v2 - mu) * inv + beta[tid + 512];
}

extern "C" void kernel_launch(void* const* d_in, const int* in_sizes, int n_in,
                              void* d_out, int out_size, void* d_ws, size_t ws_size,
                              hipStream_t stream) {
  const float* X      = (const float*)d_in[0];
  const float* Wq     = (const float*)d_in[1];
  const float* bq     = (const float*)d_in[2];
  const float* Wk     = (const float*)d_in[3];
  const float* bk     = (const float*)d_in[4];
  const float* Wv     = (const float*)d_in[5];
  const float* bv     = (const float*)d_in[6];
  const float* conv_w = (const float*)d_in[7];
  const float* conv_b = (const float*)d_in[8];
  const float* Wo     = (const float*)d_in[9];
  const float* bo     = (const float*)d_in[10];
  const float* gamma  = (const float*)d_in[11];
  const float* beta   = (const float*)d_in[12];
  float* out = (float*)d_out;                  // reference output dtype is FLOAT32
  char* ws = (char*)d_ws;

  // workspace layout (bytes, 16B-aligned). Peak footprint ~196.5 MiB via aliasing:
  //   [ Wqkvt | Wot | bias | Xb(=CtxT later) | QKV(=A2,res later) ]
  const size_t o_Wqkvt = 0;                            // 2304*768*2  = 3,538,944
  const size_t o_Wot   = o_Wqkvt + 3538944;            // 768*768*2   = 1,179,648
  const size_t o_bias  = o_Wot + 1179648;              // 2304*4      = 9,216
  const size_t o_Xb    = o_bias + 9216;                // 32768*768*2 = 50,331,648
  const size_t o_QKV   = o_Xb + 50331648;              // 32768*2304*2= 150,994,944
  const size_t o_CtxT  = o_Xb;                         // Xb dead after gemm1
  const size_t o_A2    = o_QKV;                        // QKV[0:50MB], dead after attn
  const size_t o_res   = o_QKV + 50331648;             // QKV[50MB:151MB] fp32 100,663,296

  u16*   Wqkvt = (u16*)(ws + o_Wqkvt);
  u16*   Wot   = (u16*)(ws + o_Wot);
  float* bqkv  = (float*)(ws + o_bias);
  u16*   Xb    = (u16*)(ws + o_Xb);
  u16*   QKV   = (u16*)(ws + o_QKV);
  u16*   CtxT  = (u16*)(ws + o_CtxT);
  u16*   A2    = (u16*)(ws + o_A2);
  float* res   = (float*)(ws + o_res);

  cast_x_kernel<<<24576, 256, 0, stream>>>(X, Xb);
  prep_wqkv_kernel<<<6912, 256, 0, stream>>>(Wq, Wk, Wv, Wqkvt);
  prep_wo_kernel<<<2304, 256, 0, stream>>>(Wo, Wot);
  prep_bias_kernel<<<9, 256, 0, stream>>>(bq, bk, bv, bqkv);

  dim3 g1(256, 18);
  gemm_kernel<0><<<g1, 256, 0, stream>>>(Xb, Wqkvt, 2304, bqkv, QKV, nullptr, nullptr);

  attn_kernel<<<4096, 128, 0, stream>>>(QKV, CtxT);        // reads QKV, writes over dead Xb

  conv_kernel<<<8 * 12 * 64, 256, 0, stream>>>(CtxT, conv_w, conv_b, A2);  // over dead QKV head

  dim3 g2(256, 6);
  gemm_kernel<1><<<g2, 256, 0, stream>>>(A2, Wot, 768, bo, nullptr, X, res); // res over dead QKV tail

  ln_kernel<<<32768, 256, 0, stream>>>(res, gamma, beta, out);
}

// Round 5
// 638.988 us; speedup vs baseline: 1.3921x; 1.3921x over previous
//
#include <hip/hip_runtime.h>

typedef unsigned short u16;
typedef unsigned int u32;
typedef __attribute__((ext_vector_type(8))) short bf16x8;
typedef __attribute__((ext_vector_type(4))) float f32x4;

__device__ __forceinline__ float bf2f(u16 h) {
  union { unsigned u; float f; } v; v.u = ((unsigned)h) << 16; return v.f;
}
__device__ __forceinline__ u16 f2bf(float f) {
  union { float f; unsigned u; } v; v.f = f;
  unsigned r = (v.u + 0x7FFFu + ((v.u >> 16) & 1u)) >> 16;
  return (u16)r;
}
__device__ __forceinline__ u32 pack2(u16 a, u16 b) { return (u32)a | ((u32)b << 16); }
__device__ __forceinline__ void gload_lds16(const void* g, void* l) {
  __builtin_amdgcn_global_load_lds((const __attribute__((address_space(1))) void*)g,
                                   (__attribute__((address_space(3))) void*)l,
                                   16, 0, 0);
}

// ---------------- prep kernels ----------------
__global__ __launch_bounds__(256) void cast_x_kernel(const float* __restrict__ X, u16* __restrict__ Xb) {
  size_t i = ((size_t)blockIdx.x * 256 + threadIdx.x) * 4;
  float4 v = *(const float4*)&X[i];
  u32 w0 = pack2(f2bf(v.x), f2bf(v.y));
  u32 w1 = pack2(f2bf(v.z), f2bf(v.w));
  *(uint2*)&Xb[i] = make_uint2(w0, w1);
}

__global__ __launch_bounds__(256) void prep_wqkv_kernel(const float* __restrict__ Wq, const float* __restrict__ Wk,
                                                        const float* __restrict__ Wv, u16* __restrict__ Wt) {
  int idx = blockIdx.x * 256 + threadIdx.x;          // over 2304*768, Wt[n][k] = W[k][n]
  if (idx >= 2304 * 768) return;
  int nn = idx / 768, k = idx - nn * 768;
  const float* src = (nn < 768) ? Wq : ((nn < 1536) ? Wk : Wv);
  int col = (nn < 768) ? nn : ((nn < 1536) ? nn - 768 : nn - 1536);
  Wt[idx] = f2bf(src[(size_t)k * 768 + col]);
}

__global__ __launch_bounds__(256) void prep_wo_kernel(const float* __restrict__ Wo, u16* __restrict__ Wt) {
  int idx = blockIdx.x * 256 + threadIdx.x;          // over 768*768
  if (idx >= 768 * 768) return;
  int nn = idx / 768, k = idx - nn * 768;
  Wt[idx] = f2bf(Wo[(size_t)k * 768 + nn]);
}

__global__ __launch_bounds__(256) void prep_bias_kernel(const float* __restrict__ bq, const float* __restrict__ bk,
                                                        const float* __restrict__ bv, float* __restrict__ bqkv) {
  int idx = blockIdx.x * 256 + threadIdx.x;
  if (idx >= 2304) return;
  bqkv[idx] = (idx < 768) ? bq[idx] : ((idx < 1536) ? bk[idx - 768] : bv[idx - 1536]);
}

// Pack conv weights into MFMA A-fragment order:
// Wp[g][t][kt][mt][lane][8], value = conv_w[(g*64 + mt*16+(lane&15))*64 + kt*32+(lane>>4)*8+j][t]
__global__ __launch_bounds__(256) void prep_wconv_kernel(const float* __restrict__ W, u16* __restrict__ Wp) {
  int idx = blockIdx.x * 256 + threadIdx.x;   // over 12*7*2*4*64*8 = 344064
  if (idx >= 344064) return;
  int j = idx & 7;
  int lane = (idx >> 3) & 63;
  int mt = (idx >> 9) & 3;
  int kt = (idx >> 11) & 1;
  int gt = idx >> 12;                         // g*7 + t
  int t = gt % 7;
  int g = gt / 7;
  int cl = mt * 16 + (lane & 15);
  int i = kt * 32 + (lane >> 4) * 8 + j;
  Wp[idx] = f2bf(W[((size_t)(g * 64 + cl) * 64 + i) * 7 + t]);
}

// ---------------- bf16 MFMA GEMM: C[M,N] = A[M,768] @ Bt[N,768]^T ----------------
template <int EPI>
__global__ __launch_bounds__(256) void gemm_kernel(const u16* __restrict__ A, const u16* __restrict__ Bt,
                                                   int N, const float* __restrict__ bias,
                                                   u16* __restrict__ Cbf,
                                                   const float* __restrict__ resid, float* __restrict__ Cf) {
  __shared__ __align__(16) u16 As[128 * 64];
  __shared__ __align__(16) u16 Bs[128 * 64];
  const int tid = threadIdx.x, lane = tid & 63, wid = tid >> 6;
  const int wr = wid >> 1, wc = wid & 1;
  const int m0 = blockIdx.x * 128, n0 = blockIdx.y * 128;
  const int lrow = lane >> 3, lcol = (lane & 7) * 8;
  f32x4 acc[4][4] = {};
  for (int k0 = 0; k0 < 768; k0 += 64) {
    #pragma unroll
    for (int it = 0; it < 4; ++it) {
      int r = it * 32 + wid * 8;
      gload_lds16(A + (size_t)(m0 + r + lrow) * 768 + k0 + lcol, &As[r * 64]);
      gload_lds16(Bt + (size_t)(n0 + r + lrow) * 768 + k0 + lcol, &Bs[r * 64]);
    }
    __syncthreads();
    #pragma unroll
    for (int kk = 0; kk < 64; kk += 32) {
      bf16x8 af[4], bfm[4];
      #pragma unroll
      for (int m = 0; m < 4; ++m)
        af[m] = *(const bf16x8*)&As[(wr * 64 + m * 16 + (lane & 15)) * 64 + kk + (lane >> 4) * 8];
      #pragma unroll
      for (int n = 0; n < 4; ++n)
        bfm[n] = *(const bf16x8*)&Bs[(wc * 64 + n * 16 + (lane & 15)) * 64 + kk + (lane >> 4) * 8];
      #pragma unroll
      for (int m = 0; m < 4; ++m)
        #pragma unroll
        for (int n = 0; n < 4; ++n)
          acc[m][n] = __builtin_amdgcn_mfma_f32_16x16x32_bf16(af[m], bfm[n], acc[m][n], 0, 0, 0);
    }
    __syncthreads();
  }
  #pragma unroll
  for (int m = 0; m < 4; ++m)
    #pragma unroll
    for (int n = 0; n < 4; ++n)
      #pragma unroll
      for (int r = 0; r < 4; ++r) {
        int row = m0 + wr * 64 + m * 16 + (lane >> 4) * 4 + r;
        int col = n0 + wc * 64 + n * 16 + (lane & 15);
        float v = acc[m][n][r] + bias[col];
        size_t idx = (size_t)row * N + col;
        if (EPI == 0) Cbf[idx] = f2bf(v);
        else          Cf[idx] = v + resid[idx];
      }
}

// ---------------- per-position 12x12 head attention ----------------
__global__ __launch_bounds__(128) void attn_kernel(const u16* __restrict__ QKV, u16* __restrict__ CtxT) {
  __shared__ __align__(16) u16 sm[8 * 2304];
  const int tid = threadIdx.x;
  const int p0 = blockIdx.x * 8;
  for (int idx = tid; idx < 8 * 288; idx += 128) {
    int rl = idx / 288, ch = idx - rl * 288;
    *(uint4*)&sm[rl * 2304 + ch * 8] = *(const uint4*)&QKV[(size_t)(p0 + rl) * 2304 + ch * 8];
  }
  __syncthreads();
  const int g = tid >> 4, j = tid & 15;
  if (j >= 12) return;
  const int row = p0 + g;
  const int b = row >> 12, s = row & 4095;
  const u16* q = &sm[g * 2304 + j * 64];
  const u16* kk = &sm[g * 2304 + 768];
  const u16* vv = &sm[g * 2304 + 1536];
  float qf[64];
  #pragma unroll
  for (int d = 0; d < 64; ++d) qf[d] = bf2f(q[d]);
  float sc[12];
  #pragma unroll
  for (int m = 0; m < 12; ++m) {
    float dot = 0.f;
    #pragma unroll
    for (int d = 0; d < 64; ++d) dot += qf[d] * bf2f(kk[m * 64 + d]);
    sc[m] = dot * 0.125f;
  }
  float mx = sc[0];
  #pragma unroll
  for (int m = 1; m < 12; ++m) mx = fmaxf(mx, sc[m]);
  float sum = 0.f;
  #pragma unroll
  for (int m = 0; m < 12; ++m) { sc[m] = __expf(sc[m] - mx); sum += sc[m]; }
  float inv = 1.f / sum;
  #pragma unroll
  for (int m = 0; m < 12; ++m) sc[m] *= inv;
  u16* outp = &CtxT[(((size_t)b * 12 + j) * 4096 + s) * 64];
  #pragma unroll
  for (int c = 0; c < 8; ++c) {
    float a[8] = {0, 0, 0, 0, 0, 0, 0, 0};
    #pragma unroll
    for (int m = 0; m < 12; ++m)
      #pragma unroll
      for (int e = 0; e < 8; ++e) a[e] += sc[m] * bf2f(vv[m * 64 + c * 8 + e]);
    uint4 st;
    st.x = pack2(f2bf(a[0]), f2bf(a[1]));
    st.y = pack2(f2bf(a[2]), f2bf(a[3]));
    st.z = pack2(f2bf(a[4]), f2bf(a[5]));
    st.w = pack2(f2bf(a[6]), f2bf(a[7]));
    *(uint4*)&outp[c * 8] = st;
  }
}

// ---------------- grouped conv as MFMA implicit GEMM ----------------
// In: CtxT [B][768][4096] bf16 (rows = channel, cols = position).
// Per (b, g, ptile of 256 positions): stage TRANSPOSED tile St[x][i] (x = position+halo,
// i = within-group channel, row = 128 B), XOR-swizzled. 7 taps = 7 shifted K=64 GEMMs.
// Out permuted to A2[b][s2][h2] bf16 (s2 = cl*64 + p/64, h2 = g*64 + p%64).
__global__ __launch_bounds__(256) void conv_mfma_kernel(const u16* __restrict__ CtxT, const u16* __restrict__ Wp,
                                                        const float* __restrict__ Bc, u16* __restrict__ A2) {
  __shared__ __align__(16) u16 St[272 * 64];   // 34,816 B
  const int blk = blockIdx.x;
  const int ptile = blk & 15;
  const int g = (blk >> 4) % 12;
  const int b = blk / (16 * 12);
  const int tid = threadIdx.x;
  const int p0 = ptile * 256;
  const size_t inbase = ((size_t)(b * 12 + g) * 64) * 4096;
  // stage: St[x][i] = ctx[g*64+i][p0 - 8 + x], x in [0,272). dword idx = x*32 + (i2 ^ ((x&7)<<2))
  {
    const int i2 = tid & 31;          // channel pair i = 2*i2, 2*i2+1
    const int xc = tid >> 5;          // 0..7
    u32* St32 = (u32*)St;
    #pragma unroll
    for (int xb = 0; xb < 5; ++xb) {
      int x0 = xb * 64 + xc * 8;
      if (x0 < 272) {
        int qp = p0 - 8 + x0;
        uint4 va = make_uint4(0, 0, 0, 0), vb = va;
        if (qp >= 0 && qp < 4096) {
          va = *(const uint4*)&CtxT[inbase + (size_t)(2 * i2) * 4096 + qp];
          vb = *(const uint4*)&CtxT[inbase + (size_t)(2 * i2 + 1) * 4096 + qp];
        }
        const u16* pa = (const u16*)&va;
        const u16* pb = (const u16*)&vb;
        #pragma unroll
        for (int j = 0; j < 8; ++j) {
          int x = x0 + j;
          St32[x * 32 + (i2 ^ ((x & 7) << 2))] = pack2(pa[j], pb[j]);
        }
      }
    }
  }
  __syncthreads();
  const int lane = tid & 63, wid = tid >> 6;
  const int pw = wid * 64;            // wave's position offset within tile
  f32x4 acc[4][4] = {};
  const u16* wg = Wp + (size_t)g * 28672;
  #pragma unroll
  for (int t = 0; t < 7; ++t) {
    #pragma unroll
    for (int kt = 0; kt < 2; ++kt) {
      const u16* wtk = wg + (size_t)((t * 2 + kt) * 4) * 512;
      bf16x8 af[4], bfr[4];
      #pragma unroll
      for (int mt = 0; mt < 4; ++mt)
        af[mt] = *(const bf16x8*)&wtk[(mt * 64 + lane) * 8];
      #pragma unroll
      for (int nt = 0; nt < 4; ++nt) {
        int xrow = pw + nt * 16 + (lane & 15) + t + 5;
        int i0 = kt * 32 + (lane >> 4) * 8;
        bfr[nt] = *(const bf16x8*)&St[xrow * 64 + (i0 ^ ((xrow & 7) << 3))];
      }
      #pragma unroll
      for (int mt = 0; mt < 4; ++mt)
        #pragma unroll
        for (int nt = 0; nt < 4; ++nt)
          acc[mt][nt] = __builtin_amdgcn_mfma_f32_16x16x32_bf16(af[mt], bfr[nt], acc[mt][nt], 0, 0, 0);
    }
  }
  #pragma unroll
  for (int mt = 0; mt < 4; ++mt) {
    #pragma unroll
    for (int r = 0; r < 4; ++r) {
      int cl = mt * 16 + (lane >> 4) * 4 + r;
      float bc = Bc[g * 64 + cl];
      #pragma unroll
      for (int nt = 0; nt < 4; ++nt) {
        int p = p0 + pw + nt * 16 + (lane & 15);
        int s2 = cl * 64 + (p >> 6);
        int h2 = g * 64 + (p & 63);
        A2[((size_t)b * 4096 + s2) * 768 + h2] = f2bf(acc[mt][nt][r] + bc);
      }
    }
  }
}

// ---------------- LayerNorm -> FLOAT32 output ----------------
__global__ __launch_bounds__(256) void ln_kernel(const float* __restrict__ res, const float* __restrict__ gamma,
                                                 const float* __restrict__ beta, float* __restrict__ out) {
  const int row = blockIdx.x, tid = threadIdx.x;
  const float* x = res + (size_t)row * 768;
  float v0 = x[tid], v1 = x[tid + 256], v2 = x[tid + 512];
  float s = v0 + v1 + v2;
  float q = v0 * v0 + v1 * v1 + v2 * v2;
  #pragma unroll
  for (int off = 32; off > 0; off >>= 1) { s += __shfl_down(s, off, 64); q += __shfl_down(q, off, 64); }
  __shared__ float sh[8];
  int w = tid >> 6;
  if ((tid & 63) == 0) { sh[w] = s; sh[4 + w] = q; }
  __syncthreads();
  float S = sh[0] + sh[1] + sh[2] + sh[3];
  float Q = sh[4] + sh[5] + sh[6] + sh[7];
  float mu = S * (1.0f / 768.0f);
  float var = Q * (1.0f / 768.0f) - mu * mu;
  float inv = rsqrtf(var + 1e-12f);
  float* o = out + (size_t)row * 768;
  o[tid]       = gamma[tid] * (v0 - mu) * inv + beta[tid];
  o[tid + 256] = gamma[tid + 256] * (v1 - mu) * inv + beta[tid + 256];
  o[tid + 512] = gamma[tid + 512] * (v2 - mu) * inv + beta[tid + 512];
}

extern "C" void kernel_launch(void* const* d_in, const int* in_sizes, int n_in,
                              void* d_out, int out_size, void* d_ws, size_t ws_size,
                              hipStream_t stream) {
  const float* X      = (const float*)d_in[0];
  const float* Wq     = (const float*)d_in[1];
  const float* bq     = (const float*)d_in[2];
  const float* Wk     = (const float*)d_in[3];
  const float* bk     = (const float*)d_in[4];
  const float* Wv     = (const float*)d_in[5];
  const float* bv     = (const float*)d_in[6];
  const float* conv_w = (const float*)d_in[7];
  const float* conv_b = (const float*)d_in[8];
  const float* Wo     = (const float*)d_in[9];
  const float* bo     = (const float*)d_in[10];
  const float* gamma  = (const float*)d_in[11];
  const float* beta   = (const float*)d_in[12];
  float* out = (float*)d_out;                  // reference output dtype is FLOAT32
  char* ws = (char*)d_ws;

  // workspace layout (bytes). Peak ~197.2 MiB via aliasing:
  const size_t o_Wqkvt = 0;                            // 2304*768*2  = 3,538,944
  const size_t o_Wot   = o_Wqkvt + 3538944;            // 768*768*2   = 1,179,648
  const size_t o_bias  = o_Wot + 1179648;              // 2304*4      = 9,216
  const size_t o_Xb    = o_bias + 9216;                // 32768*768*2 = 50,331,648
  const size_t o_QKV   = o_Xb + 50331648;              // 32768*2304*2= 150,994,944
  const size_t o_CtxT  = o_Xb;                         // Xb dead after gemm1
  const size_t o_A2    = o_QKV;                        // QKV[0:50MB], dead after attn
  const size_t o_res   = o_QKV + 50331648;             // QKV[50MB:151MB] fp32
  const size_t o_Wp    = o_QKV + 150994944;            // 344064*2 = 688,128 -> end 206,742,528

  u16*   Wqkvt = (u16*)(ws + o_Wqkvt);
  u16*   Wot   = (u16*)(ws + o_Wot);
  float* bqkv  = (float*)(ws + o_bias);
  u16*   Xb    = (u16*)(ws + o_Xb);
  u16*   QKV   = (u16*)(ws + o_QKV);
  u16*   CtxT  = (u16*)(ws + o_CtxT);
  u16*   A2    = (u16*)(ws + o_A2);
  float* res   = (float*)(ws + o_res);
  u16*   Wp    = (u16*)(ws + o_Wp);

  cast_x_kernel<<<24576, 256, 0, stream>>>(X, Xb);
  prep_wqkv_kernel<<<6912, 256, 0, stream>>>(Wq, Wk, Wv, Wqkvt);
  prep_wo_kernel<<<2304, 256, 0, stream>>>(Wo, Wot);
  prep_bias_kernel<<<9, 256, 0, stream>>>(bq, bk, bv, bqkv);
  prep_wconv_kernel<<<1344, 256, 0, stream>>>(conv_w, Wp);

  dim3 g1(256, 18);
  gemm_kernel<0><<<g1, 256, 0, stream>>>(Xb, Wqkvt, 2304, bqkv, QKV, nullptr, nullptr);

  attn_kernel<<<4096, 128, 0, stream>>>(QKV, CtxT);        // reads QKV, writes over dead Xb

  conv_mfma_kernel<<<8 * 12 * 16, 256, 0, stream>>>(CtxT, Wp, conv_b, A2);

  dim3 g2(256, 6);
  gemm_kernel<1><<<g2, 256, 0, stream>>>(A2, Wot, 768, bo, nullptr, X, res);

  ln_kernel<<<32768, 256, 0, stream>>>(res, gamma, beta, out);
}